// Round 12
// baseline (564.180 us; speedup 1.0000x reference)
//
#include <hip/hip_runtime.h>
#include <hip/hip_fp16.h>

// ---------------------------------------------------------------------------
// EdgeClassifierGNN: 2x SAGEConv(mean)+BN+ReLU, then 3-layer edge MLP.
// Trick 1: lin_l before mean-aggregation (64-wide gather).
// Trick 3: CSR by dst -> atomic-free aggregation; k_edge in dst order.
// Trick 4: node linears via register-blocked GEMM, BN fused on input.
// Trick 6: k_edge layer 2 via v_mfma_f32_16x16x32_f16 + shfl epilogue.
// Trick 7 (r9): k_agg wave-per-node with 8-edges-per-load gather + butterfly.
// Trick 10 (r12): k_edge layer 1 ALSO via MFMA on gathered 64-dim fp16 node
//          features (single 6.4 MB table, A-frags straight from the loads).
// Trick 12 (r17): attr pre-gathered to CSR order as fp16 (attrC) in k_fill.
// Trick 13 (r19): nc-outer layer-1 -> acc retires per-nc; (256,2) spill-free
//          (r10 proof: WRITE == exact 6.25MB out2 payload, k_edge 96.7us).
// Trick 14 (r20): csr (src,dst) packed int2; k_finalize folded into
//          k_gemm/k_bn LDS prologues. (Index prefetch tried r20, neutral +
//          3MB spill -> reverted r21. Prefetch scoreboard: 0 wins / 5 tries.)
// Trick 15 (r21): k_agg grid 1024->2048: at ~40 VGPR / 2KB LDS the machine
//          holds 2048 blocks resident; 1024 left half the latency-hiding
//          capacity unused in a serial-node latency-bound kernel.
// ---------------------------------------------------------------------------

#define EPS 1e-5f

typedef _Float16 h8 __attribute__((ext_vector_type(8)));
typedef float f32x4 __attribute__((ext_vector_type(4)));

// ---------------- CSR build + weight prep (merged) ----------------
// prep elements: Wt1 16384 | Wt2 8192 | bias1 128 | bias2 128 | W2B 8192 |
//                W1B 20480  => 53504 total
__global__ __launch_bounds__(256) void k_prep_hist(
    const float* __restrict__ W1l, const float* __restrict__ W1r,
    const float* __restrict__ b1l,
    const float* __restrict__ W2l, const float* __restrict__ W2r,
    const float* __restrict__ b2l,
    const float* __restrict__ Wm1, const float* __restrict__ Wm2,
    float* __restrict__ Wt1, float* __restrict__ Wt2,
    float* __restrict__ bias1, float* __restrict__ bias2,
    __half* __restrict__ W2B, __half* __restrict__ W1B,
    const int* __restrict__ dst, int* __restrict__ deg, int E, int prepBlocks) {
  if ((int)blockIdx.x >= prepBlocks) {
    int e = (blockIdx.x - prepBlocks) * 256 + threadIdx.x;
    if (e < E) atomicAdd(&deg[dst[e]], 1);
    return;
  }
  int idx = blockIdx.x * 256 + threadIdx.x;
  if (idx < 16384) {  // Wt1 [128k x 128f] = [W1l | W1r]^T
    int k = idx >> 7, f = idx & 127;
    Wt1[idx] = (f < 64) ? W1l[f * 128 + k] : W1r[(f - 64) * 128 + k];
    return;
  }
  idx -= 16384;
  if (idx < 8192) {   // Wt2 [64k x 128f] = [W2l | W2r]^T
    int k = idx >> 7, f = idx & 127;
    Wt2[idx] = (f < 64) ? W2l[f * 64 + k] : W2r[(f - 64) * 64 + k];
    return;
  }
  idx -= 8192;
  if (idx < 128) { bias1[idx] = (idx < 64) ? 0.f : b1l[idx - 64]; return; }
  idx -= 128;
  if (idx < 128) { bias2[idx] = (idx < 64) ? 0.f : b2l[idx - 64]; return; }
  idx -= 128;
  if (idx < 8192) {   // W2B: Wm2^T pre-swizzled to MFMA B-fragment layout
    int j = idx & 7, l = (idx >> 3) & 63, f = idx >> 9;
    int kc = f >> 2, tt = f & 3;
    int col = 16 * tt + (l & 15);
    int k = 32 * kc + (l >> 4) * 8 + j;
    W2B[idx] = __float2half(Wm2[col * 128 + k]);
    return;
  }
  idx -= 8192;
  if (idx < 20480) {  // W1B: layer-1 Wcat (160x128) in MFMA B-fragment layout
    int j = idx & 7, l = (idx >> 3) & 63, f = idx >> 9;  // f = kc*8+nc, 0..39
    int kc = f >> 3, nc = f & 7;
    int k = 32 * kc + (l >> 4) * 8 + j;   // 0..159
    int n = 16 * nc + (l & 15);           // 0..127
    float w;
    if (k < 64)       w = Wm1[n * 144 + k];            // src cols 0..63
    else if (k < 128) w = Wm1[n * 144 + 80 + (k - 64)];// dst cols 80..143
    else if (k < 144) w = Wm1[n * 144 + 64 + (k - 128)];// attr cols 64..79
    else              w = 0.f;                          // pad
    W1B[idx] = __float2half(w);
    return;
  }
}

__global__ __launch_bounds__(1024) void k_scan(
    const int* __restrict__ deg, int* __restrict__ rowptr,
    int* __restrict__ cursor, int N) {
  __shared__ int wsum[16];
  __shared__ int carry;
  const int lane = threadIdx.x & 63;
  const int w    = threadIdx.x >> 6;
  if (threadIdx.x == 0) carry = 0;
  __syncthreads();
  for (int base = 0; base < N; base += 1024) {
    int i = base + threadIdx.x;
    int v = (i < N) ? deg[i] : 0;
    int incl = v;
#pragma unroll
    for (int off = 1; off < 64; off <<= 1) {
      int t = __shfl_up(incl, off);
      if (lane >= off) incl += t;
    }
    if (lane == 63) wsum[w] = incl;
    __syncthreads();
    if (w == 0) {
      int ws_ = (lane < 16) ? wsum[lane] : 0;
      int wincl = ws_;
#pragma unroll
      for (int off = 1; off < 16; off <<= 1) {
        int t = __shfl_up(wincl, off);
        if (lane >= off) wincl += t;
      }
      if (lane < 16) wsum[lane] = wincl;
    }
    __syncthreads();
    int woff = carry + (w > 0 ? wsum[w - 1] : 0);
    int excl = woff + incl - v;
    if (i < N) { rowptr[i] = excl; cursor[i] = excl; }
    int tot = wsum[15];
    __syncthreads();
    if (threadIdx.x == 0) carry += tot;
    __syncthreads();
  }
  if (threadIdx.x == 0) rowptr[N] = carry;
}

// CSR scatter (packed int2); records pos[eid]; pre-gathers attr as fp16.
__global__ __launch_bounds__(256) void k_fill(
    const int* __restrict__ src, const int* __restrict__ dst,
    const float* __restrict__ attr,
    int* __restrict__ cursor, int2* __restrict__ csr_sd,
    int* __restrict__ pos, __half* __restrict__ attrC, int E) {
  int e = blockIdx.x * 256 + threadIdx.x;
  if (e < E) {
    int d = dst[e];
    int p = atomicAdd(&cursor[d], 1);
    csr_sd[p] = make_int2(src[e], d);
    pos[e] = p;
    const float4* at4 = (const float4*)attr;
    float4 a0 = at4[(size_t)e * 4 + 0];
    float4 a1 = at4[(size_t)e * 4 + 1];
    float4 a2 = at4[(size_t)e * 4 + 2];
    float4 a3 = at4[(size_t)e * 4 + 3];
    __half2 hh[8];
    hh[0] = __floats2half2_rn(a0.x, a0.y);
    hh[1] = __floats2half2_rn(a0.z, a0.w);
    hh[2] = __floats2half2_rn(a1.x, a1.y);
    hh[3] = __floats2half2_rn(a1.z, a1.w);
    hh[4] = __floats2half2_rn(a2.x, a2.y);
    hh[5] = __floats2half2_rn(a2.z, a2.w);
    hh[6] = __floats2half2_rn(a3.x, a3.y);
    hh[7] = __floats2half2_rn(a3.z, a3.w);
    *(uint4*)&attrC[(size_t)p * 16]     = *(uint4*)&hh[0];
    *(uint4*)&attrC[(size_t)p * 16 + 8] = *(uint4*)&hh[4];
  }
}

// final inverse-permute: coalesced write of out, gather from L2-resident out2
__global__ __launch_bounds__(256) void k_scatter_out(
    const float* __restrict__ out2, const int* __restrict__ pos,
    float* __restrict__ out, int E) {
  int e = blockIdx.x * 256 + threadIdx.x;
  if (e < E) {
    int p = pos[e];
    *(float2*)&out[(size_t)e * 2] = *(const float2*)&out2[(size_t)p * 2];
  }
}

// ---------------- register-blocked node GEMM ----------------
// When stats != nullptr: BN scale/shift computed from RAW stats sums in an
// LDS prologue (k_finalize folded in); input transform = relu(x*sc+sh).
template<int K, int MODE>
__global__ __launch_bounds__(256) void k_gemm(
    const float* __restrict__ X, const float* __restrict__ stats,
    const float* __restrict__ gma, const float* __restrict__ bta,
    const float* __restrict__ Wt, const float* __restrict__ bias,
    __half* __restrict__ outH, float* __restrict__ outF, int N, int Ftot) {
  __shared__ __align__(16) float Xs[32][68];
  __shared__ __align__(16) float Ws_[32][128];
  __shared__ float scs[64], shs[64];
  const int tid = threadIdx.x;
  const int tx  = tid & 15;
  const int ty  = tid >> 4;
  const int n0  = blockIdx.x * 64;
  if (stats && tid < 64) {
    float inv_n = 1.0f / (float)N;
    float mean = stats[tid] * inv_n;
    float var  = stats[64 + tid] * inv_n - mean * mean;
    float s = gma[tid] * rsqrtf(var + EPS);
    scs[tid] = s;
    shs[tid] = bta[tid] - mean * s;
  }
  float acc[4][8];
#pragma unroll
  for (int j = 0; j < 8; ++j) {
    float bv = bias[8 * tx + j];
#pragma unroll
    for (int i = 0; i < 4; ++i) acc[i][j] = bv;
  }
  for (int k0 = 0; k0 < K; k0 += 32) {
    __syncthreads();
#pragma unroll
    for (int l = 0; l < 2; ++l) {
      int idx = tid * 2 + l;
      int kq = idx & 7, n = idx >> 3;
      float4 xv = make_float4(0.f, 0.f, 0.f, 0.f);
      if (n0 + n < N) xv = *(const float4*)&X[(size_t)(n0 + n) * K + k0 + kq * 4];
      if (stats) {
        int kb = k0 + kq * 4;
        xv.x = fmaxf(xv.x * scs[kb + 0] + shs[kb + 0], 0.f);
        xv.y = fmaxf(xv.y * scs[kb + 1] + shs[kb + 1], 0.f);
        xv.z = fmaxf(xv.z * scs[kb + 2] + shs[kb + 2], 0.f);
        xv.w = fmaxf(xv.w * scs[kb + 3] + shs[kb + 3], 0.f);
      }
      Xs[kq * 4 + 0][n] = xv.x;
      Xs[kq * 4 + 1][n] = xv.y;
      Xs[kq * 4 + 2][n] = xv.z;
      Xs[kq * 4 + 3][n] = xv.w;
    }
#pragma unroll
    for (int l = 0; l < 4; ++l) {
      int idx = tid + l * 256;
      int kr = idx >> 5, fc = idx & 31;
      *(float4*)&Ws_[kr][fc * 4] =
          *(const float4*)&Wt[(size_t)(k0 + kr) * Ftot + fc * 4];
    }
    __syncthreads();
#pragma unroll
    for (int kk = 0; kk < 32; ++kk) {
      float4 a  = *(const float4*)&Xs[kk][4 * ty];
      float4 b0 = *(const float4*)&Ws_[kk][8 * tx];
      float4 b1 = *(const float4*)&Ws_[kk][8 * tx + 4];
      float aa[4] = {a.x, a.y, a.z, a.w};
      float bb[8] = {b0.x, b0.y, b0.z, b0.w, b1.x, b1.y, b1.z, b1.w};
#pragma unroll
      for (int i = 0; i < 4; ++i)
#pragma unroll
        for (int j = 0; j < 8; ++j) acc[i][j] += aa[i] * bb[j];
    }
  }
#pragma unroll
  for (int i = 0; i < 4; ++i) {
    int n = n0 + 4 * ty + i;
    if (n >= N) continue;
    if (tx < 8) {
      __half2 hh[4];
#pragma unroll
      for (int c = 0; c < 4; ++c)
        hh[c] = __floats2half2_rn(acc[i][2 * c], acc[i][2 * c + 1]);
      *(uint4*)&outH[(size_t)n * 64 + 8 * tx] = *(uint4*)hh;
    } else {
      float* cp = outF + (size_t)n * 64 + 8 * tx - 64;
      *(float4*)cp = make_float4(acc[i][0], acc[i][1], acc[i][2], acc[i][3]);
      *(float4*)(cp + 4) = make_float4(acc[i][4], acc[i][5], acc[i][6], acc[i][7]);
    }
  }
}

// ---------------- fused aggregate + mean + residual + BN stats ----------------
__global__ __launch_bounds__(256) void k_agg(
    const __half* __restrict__ qb, const float* __restrict__ pb,
    const int* __restrict__ rowptr, const int2* __restrict__ csr_sd,
    float* __restrict__ hpre, float* __restrict__ stats, int N) {
  __shared__ float red[512];
  const int tid  = threadIdx.x;
  const int w    = tid >> 6;
  const int lane = tid & 63;
  const int g    = lane >> 3, c = lane & 7;
  float lsum = 0.f, lsq = 0.f;
  const int wid = blockIdx.x * 4 + w;
  const int nw  = gridDim.x * 4;
  for (int n = wid; n < N; n += nw) {
    const int r0 = rowptr[n], r1 = rowptr[n + 1];
    float s[8] = {0.f, 0.f, 0.f, 0.f, 0.f, 0.f, 0.f, 0.f};
    for (int j = r0 + g; j < r1; j += 8) {
      int a = csr_sd[j].x;
      uint4 rv = *(const uint4*)&qb[(size_t)a * 64 + 8 * c];
      const __half2* hp = (const __half2*)&rv;
#pragma unroll
      for (int q = 0; q < 4; ++q) {
        float2 f2 = __half22float2(hp[q]);
        s[2 * q]     += f2.x;
        s[2 * q + 1] += f2.y;
      }
    }
#pragma unroll
    for (int m = 8; m < 64; m <<= 1)
#pragma unroll
      for (int q = 0; q < 8; ++q) s[q] += __shfl_xor(s[q], m);
    float sv = s[0];
#pragma unroll
    for (int q = 1; q < 8; ++q) sv = (g == q) ? s[q] : sv;
    float cdeg = (float)(r1 - r0);
    cdeg = cdeg > 1.f ? cdeg : 1.f;
    const int f = 8 * c + g;
    float v = sv / cdeg + pb[(size_t)n * 64 + f];
    hpre[(size_t)n * 64 + f] = v;
    lsum += v;
    lsq  += v * v;
  }
  red[tid]       = lsum;
  red[256 + tid] = lsq;
  __syncthreads();
  if (tid < 64) {
    float ts = red[tid] + red[tid + 64] + red[tid + 128] + red[tid + 192];
    float tq = red[256 + tid] + red[256 + tid + 64] + red[256 + tid + 128] + red[256 + tid + 192];
    int f = 8 * (tid & 7) + (tid >> 3);
    atomicAdd(&stats[f], ts);
    atomicAdd(&stats[64 + f], tq);
  }
}

// BN2+relu -> fp16 node features h2; scale/shift from RAW stats (finalize
// folded into a 64-thread LDS prologue per block).
__global__ __launch_bounds__(256) void k_bn(
    const float* __restrict__ H1, const float* __restrict__ stats,
    const float* __restrict__ g, const float* __restrict__ be,
    __half* __restrict__ H2, int N) {
  __shared__ float scs[64], shs[64];
  const int tid = threadIdx.x;
  if (tid < 64) {
    float inv_n = 1.0f / (float)N;
    float mean = stats[tid] * inv_n;
    float var  = stats[64 + tid] * inv_n - mean * mean;
    float s = g[tid] * rsqrtf(var + EPS);
    scs[tid] = s;
    shs[tid] = be[tid] - mean * s;
  }
  __syncthreads();
  int idx = blockIdx.x * 256 + tid;
  if (idx >= N * 8) return;
  int n = idx >> 3, f8 = (idx & 7) * 8;
  float4 h0 = *(const float4*)&H1[(size_t)n * 64 + f8];
  float4 h1 = *(const float4*)&H1[(size_t)n * 64 + f8 + 4];
  __half2 hh[4];
  hh[0] = __floats2half2_rn(fmaxf(h0.x * scs[f8 + 0] + shs[f8 + 0], 0.f),
                            fmaxf(h0.y * scs[f8 + 1] + shs[f8 + 1], 0.f));
  hh[1] = __floats2half2_rn(fmaxf(h0.z * scs[f8 + 2] + shs[f8 + 2], 0.f),
                            fmaxf(h0.w * scs[f8 + 3] + shs[f8 + 3], 0.f));
  hh[2] = __floats2half2_rn(fmaxf(h1.x * scs[f8 + 4] + shs[f8 + 4], 0.f),
                            fmaxf(h1.y * scs[f8 + 5] + shs[f8 + 5], 0.f));
  hh[3] = __floats2half2_rn(fmaxf(h1.z * scs[f8 + 6] + shs[f8 + 6], 0.f),
                            fmaxf(h1.w * scs[f8 + 7] + shs[f8 + 7], 0.f));
  *(uint4*)&H2[(size_t)n * 64 + f8] = *(uint4*)hh;
}

// ---------------------------------------------------------------------------
// Fused edge MLP, all-MFMA, straight-line body, nc-outer layer-1.
// (256,2): VGPR<=128 -> 2 blocks/CU (LDS 74.75KB x2 = 149.5 <= 160 KB).
// ---------------------------------------------------------------------------
__global__ __launch_bounds__(256, 2) void k_edge(
    const __half* __restrict__ H2, const __half* __restrict__ attrC,
    const int2* __restrict__ csd,
    const __half* __restrict__ W1Bws, const __half* __restrict__ W2Bws,
    const float* __restrict__ bm1, const float* __restrict__ bm2,
    const float* __restrict__ Wm3, const float* __restrict__ bm3,
    float* __restrict__ out2, int E) {
  __shared__ __align__(16) _Float16 W1B[20480];
  __shared__ __align__(16) _Float16 W2B[8192];
  __shared__ __align__(16) _Float16 Z1f[64 * 136];

  const int tid  = threadIdx.x;
  const int lane = tid & 63;
  const int w    = tid >> 6;
  const int ln15 = lane & 15;
  const int quad = lane >> 4;

  for (int i = tid; i < 2560; i += 256)
    ((uint4*)W1B)[i] = ((const uint4*)W1Bws)[i];
  for (int i = tid; i < 1024; i += 256)
    ((uint4*)W2B)[i] = ((const uint4*)W2Bws)[i];

  float bm1v[8];
#pragma unroll
  for (int nc = 0; nc < 8; ++nc) bm1v[nc] = bm1[16 * nc + ln15];
  float bmv[4], w30[4], w31[4];
#pragma unroll
  for (int t = 0; t < 4; ++t) {
    bmv[t] = bm2[16 * t + ln15];
    w30[t] = Wm3[16 * t + ln15];
    w31[t] = Wm3[64 + 16 * t + ln15];
  }
  const float bm30 = bm3[0], bm31 = bm3[1];
  __syncthreads();

  const int nt = (E + 63) >> 6;
  const int rowoff = 16 * w + ln15;

  for (int t = blockIdx.x; t < nt; t += gridDim.x) {
    int er = (t << 6) + rowoff;
    if (er >= E) er = E - 1;
    const int2 sd = csd[er];
    const int s = sd.x;
    const int d = sd.y;

    // A-fragments straight from gathers: row = ln15, k-halves = quad*8..+7
    h8 af0 = *(const h8*)&H2[(size_t)s * 64 + 8 * quad];
    h8 af1 = *(const h8*)&H2[(size_t)s * 64 + 32 + 8 * quad];
    h8 af2 = *(const h8*)&H2[(size_t)d * 64 + 8 * quad];
    h8 af3 = *(const h8*)&H2[(size_t)d * 64 + 32 + 8 * quad];
    h8 af4 = (h8){0, 0, 0, 0, 0, 0, 0, 0};
    if (quad < 2)
      af4 = *(const h8*)&attrC[(size_t)er * 16 + 8 * quad];  // coalesced

    // ---- layer 1 (nc outer: each acc retires to Z1f after its 5 MFMAs) ----
    const int ebase = 16 * w + 4 * quad;
#pragma unroll
    for (int nc = 0; nc < 8; ++nc) {
      f32x4 a1 = (f32x4){bm1v[nc], bm1v[nc], bm1v[nc], bm1v[nc]};
      a1 = __builtin_amdgcn_mfma_f32_16x16x32_f16(
          af0, *(const h8*)&W1B[((0 * 8 + nc) << 9) + (lane << 3)], a1, 0, 0, 0);
      a1 = __builtin_amdgcn_mfma_f32_16x16x32_f16(
          af1, *(const h8*)&W1B[((1 * 8 + nc) << 9) + (lane << 3)], a1, 0, 0, 0);
      a1 = __builtin_amdgcn_mfma_f32_16x16x32_f16(
          af2, *(const h8*)&W1B[((2 * 8 + nc) << 9) + (lane << 3)], a1, 0, 0, 0);
      a1 = __builtin_amdgcn_mfma_f32_16x16x32_f16(
          af3, *(const h8*)&W1B[((3 * 8 + nc) << 9) + (lane << 3)], a1, 0, 0, 0);
      a1 = __builtin_amdgcn_mfma_f32_16x16x32_f16(
          af4, *(const h8*)&W1B[((4 * 8 + nc) << 9) + (lane << 3)], a1, 0, 0, 0);
      Z1f[(ebase + 0) * 136 + 16 * nc + ln15] = (_Float16)fmaxf(a1[0], 0.f);
      Z1f[(ebase + 1) * 136 + 16 * nc + ln15] = (_Float16)fmaxf(a1[1], 0.f);
      Z1f[(ebase + 2) * 136 + 16 * nc + ln15] = (_Float16)fmaxf(a1[2], 0.f);
      Z1f[(ebase + 3) * 136 + 16 * nc + ln15] = (_Float16)fmaxf(a1[3], 0.f);
    }

    // ---- layer 2 (wave-local rows; no cross-wave sync needed) ----
    f32x4 acc2[4];
#pragma unroll
    for (int tt = 0; tt < 4; ++tt)
      acc2[tt] = (f32x4){bmv[tt], bmv[tt], bmv[tt], bmv[tt]};
#pragma unroll
    for (int kc = 0; kc < 4; ++kc) {
      h8 a = *(const h8*)&Z1f[(16 * w + ln15) * 136 + 32 * kc + 8 * quad];
#pragma unroll
      for (int tt = 0; tt < 4; ++tt) {
        h8 bf = *(const h8*)&W2B[((kc * 4 + tt) * 64 + lane) * 8];
        acc2[tt] = __builtin_amdgcn_mfma_f32_16x16x32_f16(a, bf, acc2[tt], 0, 0, 0);
      }
    }

    // ---- layer 3 + output (coalesced, CSR order) ----
    float p0[4], p1[4];
#pragma unroll
    for (int r = 0; r < 4; ++r) { p0[r] = 0.f; p1[r] = 0.f; }
#pragma unroll
    for (int tt = 0; tt < 4; ++tt)
#pragma unroll
      for (int r = 0; r < 4; ++r) {
        float z = fmaxf(acc2[tt][r], 0.f);
        p0[r] += z * w30[tt];
        p1[r] += z * w31[tt];
      }
#pragma unroll
    for (int r = 0; r < 4; ++r) {
#pragma unroll
      for (int m = 1; m < 16; m <<= 1) {
        p0[r] += __shfl_xor(p0[r], m);
        p1[r] += __shfl_xor(p1[r], m);
      }
      if (ln15 == 0) {
        int j = (t << 6) + 16 * w + 4 * quad + r;
        if (j < E)
          *(float2*)&out2[(size_t)j * 2] = make_float2(p0[r] + bm30, p1[r] + bm31);
      }
    }
  }
}

extern "C" void kernel_launch(void* const* d_in, const int* in_sizes, int n_in,
                              void* d_out, int out_size, void* d_ws, size_t ws_size,
                              hipStream_t stream) {
  const float* x    = (const float*)d_in[0];
  const int*   ei   = (const int*)d_in[1];
  const float* attr = (const float*)d_in[2];
  const float* W1l  = (const float*)d_in[3];
  const float* b1l  = (const float*)d_in[4];
  const float* W1r  = (const float*)d_in[5];
  const float* g1   = (const float*)d_in[6];
  const float* be1  = (const float*)d_in[7];
  const float* W2l  = (const float*)d_in[8];
  const float* b2l  = (const float*)d_in[9];
  const float* W2r  = (const float*)d_in[10];
  const float* g2   = (const float*)d_in[11];
  const float* be2  = (const float*)d_in[12];
  const float* Wm1  = (const float*)d_in[13];
  const float* bm1  = (const float*)d_in[14];
  const float* Wm2  = (const float*)d_in[15];
  const float* bm2  = (const float*)d_in[16];
  const float* Wm3  = (const float*)d_in[17];
  const float* bm3  = (const float*)d_in[18];
  float* out = (float*)d_out;

  const int N = in_sizes[0] / 128;
  const int E = in_sizes[1] / 2;
  const int* srcI = ei;
  const int* dstI = ei + E;

  float* ws = (float*)d_ws;
  const size_t NF = (size_t)N * 64;
  float*  P32 = ws;                        // [N][64] f32
  float*  H1  = ws + NF;                   // [N][64] f32 (reused as H2pre)
  __half* Q16 = (__half*)(ws + 2 * NF);    // [N][64] f16 (later: H2 table)
  float* small  = ws + 2 * NF + NF / 2;
  float* stats1 = small;          // 256
  float* stats2 = stats1 + 256;   // 256
  float* Wt1    = stats2 + 256;   // 128*128
  float* Wt2    = Wt1 + 16384;    // 64*128
  float* bias1  = Wt2 + 8192;     // 128
  float* bias2  = bias1 + 128;    // 128
  __half* W1B   = (__half*)(bias2 + 128);            // 20480 halves = 10240 f
  __half* W2B   = (__half*)(bias2 + 128 + 10240);    // 8192 halves = 4096 f
  int2* csr_sd = (int2*)(bias2 + 128 + 10240 + 4096); // E int2 (8B-aligned)
  int* rowptr = (int*)(csr_sd + E);         // N+1
  int* cursor = rowptr + (N + 1);           // N
  int* deg    = cursor + N;                 // N
  int* pos    = deg + N;                    // E
  __half* attrC = (__half*)(((uintptr_t)(pos + E) + 15) & ~(uintptr_t)15);

  __half* H2  = Q16;   // Q16 dead after 2nd k_agg; k_bn writes H2 there
  float* out2 = H1;    // H1 dead after k_bn reads it

  hipMemsetAsync(deg, 0, (size_t)N * sizeof(int), stream);
  hipMemsetAsync(stats1, 0, 512 * sizeof(float), stream);

  // ---- weight prep + degree histogram (one launch) ----
  const int eBlocks = (E + 255) / 256;
  const int prepBlocks = (53504 + 255) / 256;
  k_prep_hist<<<prepBlocks + eBlocks, 256, 0, stream>>>(
      W1l, W1r, b1l, W2l, W2r, b2l, Wm1, Wm2,
      Wt1, Wt2, bias1, bias2, W2B, W1B,
      dstI, deg, E, prepBlocks);
  k_scan<<<1, 1024, 0, stream>>>(deg, rowptr, cursor, N);
  k_fill<<<eBlocks, 256, 0, stream>>>(srcI, dstI, attr, cursor,
                                      csr_sd, pos, attrC, E);

  const int mTiles = (N + 63) / 64;

  // ---- conv1: Q16 = fp16(x@W1l^T), P32 = x@W1r^T + b1l ----
  k_gemm<128, 0><<<mTiles, 256, 0, stream>>>(x, nullptr, nullptr, nullptr,
                                             Wt1, bias1, Q16, P32, N, 128);
  k_agg<<<2048, 256, 0, stream>>>(Q16, P32, rowptr, csr_sd, H1, stats1, N);

  // ---- conv2 (BN1+relu computed from raw stats in-gemm) ----
  k_gemm<64, 0><<<mTiles, 256, 0, stream>>>(H1, stats1, g1, be1,
                                            Wt2, bias2, Q16, P32, N, 128);
  k_agg<<<2048, 256, 0, stream>>>(Q16, P32, rowptr, csr_sd, H1, stats2, N);

  // ---- BN2+relu -> fp16 h2 table (finalize folded in) ----
  k_bn<<<(N * 8 + 255) / 256, 256, 0, stream>>>(H1, stats2, g2, be2, H2, N);

  // ---- fused all-MFMA edge MLP over dst-CSR edges, coalesced out2 ----
  k_edge<<<1024, 256, 0, stream>>>(H2, attrC, csr_sd,
                                   W1B, W2B, bm1, bm2, Wm3, bm3, out2, E);
  // ---- inverse-permute to final output order ----
  k_scatter_out<<<eBlocks, 256, 0, stream>>>(out2, pos, out, E);
}

// Round 13
// 492.947 us; speedup vs baseline: 1.1445x; 1.1445x over previous
//
#include <hip/hip_runtime.h>
#include <hip/hip_fp16.h>

// ---------------------------------------------------------------------------
// EdgeClassifierGNN: 2x SAGEConv(mean)+BN+ReLU, then 3-layer edge MLP.
// Trick 1: lin_l before mean-aggregation (64-wide gather).
// Trick 3: CSR by dst -> atomic-free aggregation; k_edge in dst order.
// Trick 4: node linears via register-blocked GEMM, BN fused on input.
// Trick 6: k_edge layer 2 via v_mfma_f32_16x16x32_f16 + shfl epilogue.
// Trick 7 (r9): k_agg wave-per-node with 8-edges-per-load gather + butterfly.
// Trick 10 (r12): k_edge layer 1 ALSO via MFMA on gathered 64-dim fp16 node
//          features (single 6.4 MB table, A-frags straight from the loads).
// Trick 12 (r17): attr pre-gathered to CSR order as fp16 (attrC) in k_fill.
// Trick 13 (r19): nc-outer layer-1 -> acc retires per-nc; (256,2) spill-free.
// Trick 14 (r20): csr (src,dst) packed int2 (k_edge 96.7->89.7us, r12);
//          k_finalize folded into k_gemm/k_bn LDS prologues.
// Trick 16 (r22): k_agg grid back to 1024 (r12 A/B: 2048 cost ~31us) and
//          8-way replicated stats accumulators: block b atomics into replica
//          b&7 -> per-address serialized atomic chain 1024 -> 128 (same-
//          address atomics serialize badly on gfx950, r1 evidence). Consumers
//          sum 8 replicas in their LDS prologues.
// ---------------------------------------------------------------------------

#define EPS 1e-5f

typedef _Float16 h8 __attribute__((ext_vector_type(8)));
typedef float f32x4 __attribute__((ext_vector_type(4)));

// ---------------- CSR build + weight prep (merged) ----------------
// prep elements: Wt1 16384 | Wt2 8192 | bias1 128 | bias2 128 | W2B 8192 |
//                W1B 20480  => 53504 total
__global__ __launch_bounds__(256) void k_prep_hist(
    const float* __restrict__ W1l, const float* __restrict__ W1r,
    const float* __restrict__ b1l,
    const float* __restrict__ W2l, const float* __restrict__ W2r,
    const float* __restrict__ b2l,
    const float* __restrict__ Wm1, const float* __restrict__ Wm2,
    float* __restrict__ Wt1, float* __restrict__ Wt2,
    float* __restrict__ bias1, float* __restrict__ bias2,
    __half* __restrict__ W2B, __half* __restrict__ W1B,
    const int* __restrict__ dst, int* __restrict__ deg, int E, int prepBlocks) {
  if ((int)blockIdx.x >= prepBlocks) {
    int e = (blockIdx.x - prepBlocks) * 256 + threadIdx.x;
    if (e < E) atomicAdd(&deg[dst[e]], 1);
    return;
  }
  int idx = blockIdx.x * 256 + threadIdx.x;
  if (idx < 16384) {  // Wt1 [128k x 128f] = [W1l | W1r]^T
    int k = idx >> 7, f = idx & 127;
    Wt1[idx] = (f < 64) ? W1l[f * 128 + k] : W1r[(f - 64) * 128 + k];
    return;
  }
  idx -= 16384;
  if (idx < 8192) {   // Wt2 [64k x 128f] = [W2l | W2r]^T
    int k = idx >> 7, f = idx & 127;
    Wt2[idx] = (f < 64) ? W2l[f * 64 + k] : W2r[(f - 64) * 64 + k];
    return;
  }
  idx -= 8192;
  if (idx < 128) { bias1[idx] = (idx < 64) ? 0.f : b1l[idx - 64]; return; }
  idx -= 128;
  if (idx < 128) { bias2[idx] = (idx < 64) ? 0.f : b2l[idx - 64]; return; }
  idx -= 128;
  if (idx < 8192) {   // W2B: Wm2^T pre-swizzled to MFMA B-fragment layout
    int j = idx & 7, l = (idx >> 3) & 63, f = idx >> 9;
    int kc = f >> 2, tt = f & 3;
    int col = 16 * tt + (l & 15);
    int k = 32 * kc + (l >> 4) * 8 + j;
    W2B[idx] = __float2half(Wm2[col * 128 + k]);
    return;
  }
  idx -= 8192;
  if (idx < 20480) {  // W1B: layer-1 Wcat (160x128) in MFMA B-fragment layout
    int j = idx & 7, l = (idx >> 3) & 63, f = idx >> 9;  // f = kc*8+nc, 0..39
    int kc = f >> 3, nc = f & 7;
    int k = 32 * kc + (l >> 4) * 8 + j;   // 0..159
    int n = 16 * nc + (l & 15);           // 0..127
    float w;
    if (k < 64)       w = Wm1[n * 144 + k];            // src cols 0..63
    else if (k < 128) w = Wm1[n * 144 + 80 + (k - 64)];// dst cols 80..143
    else if (k < 144) w = Wm1[n * 144 + 64 + (k - 128)];// attr cols 64..79
    else              w = 0.f;                          // pad
    W1B[idx] = __float2half(w);
    return;
  }
}

__global__ __launch_bounds__(1024) void k_scan(
    const int* __restrict__ deg, int* __restrict__ rowptr,
    int* __restrict__ cursor, int N) {
  __shared__ int wsum[16];
  __shared__ int carry;
  const int lane = threadIdx.x & 63;
  const int w    = threadIdx.x >> 6;
  if (threadIdx.x == 0) carry = 0;
  __syncthreads();
  for (int base = 0; base < N; base += 1024) {
    int i = base + threadIdx.x;
    int v = (i < N) ? deg[i] : 0;
    int incl = v;
#pragma unroll
    for (int off = 1; off < 64; off <<= 1) {
      int t = __shfl_up(incl, off);
      if (lane >= off) incl += t;
    }
    if (lane == 63) wsum[w] = incl;
    __syncthreads();
    if (w == 0) {
      int ws_ = (lane < 16) ? wsum[lane] : 0;
      int wincl = ws_;
#pragma unroll
      for (int off = 1; off < 16; off <<= 1) {
        int t = __shfl_up(wincl, off);
        if (lane >= off) wincl += t;
      }
      if (lane < 16) wsum[lane] = wincl;
    }
    __syncthreads();
    int woff = carry + (w > 0 ? wsum[w - 1] : 0);
    int excl = woff + incl - v;
    if (i < N) { rowptr[i] = excl; cursor[i] = excl; }
    int tot = wsum[15];
    __syncthreads();
    if (threadIdx.x == 0) carry += tot;
    __syncthreads();
  }
  if (threadIdx.x == 0) rowptr[N] = carry;
}

// CSR scatter (packed int2); records pos[eid]; pre-gathers attr as fp16.
__global__ __launch_bounds__(256) void k_fill(
    const int* __restrict__ src, const int* __restrict__ dst,
    const float* __restrict__ attr,
    int* __restrict__ cursor, int2* __restrict__ csr_sd,
    int* __restrict__ pos, __half* __restrict__ attrC, int E) {
  int e = blockIdx.x * 256 + threadIdx.x;
  if (e < E) {
    int d = dst[e];
    int p = atomicAdd(&cursor[d], 1);
    csr_sd[p] = make_int2(src[e], d);
    pos[e] = p;
    const float4* at4 = (const float4*)attr;
    float4 a0 = at4[(size_t)e * 4 + 0];
    float4 a1 = at4[(size_t)e * 4 + 1];
    float4 a2 = at4[(size_t)e * 4 + 2];
    float4 a3 = at4[(size_t)e * 4 + 3];
    __half2 hh[8];
    hh[0] = __floats2half2_rn(a0.x, a0.y);
    hh[1] = __floats2half2_rn(a0.z, a0.w);
    hh[2] = __floats2half2_rn(a1.x, a1.y);
    hh[3] = __floats2half2_rn(a1.z, a1.w);
    hh[4] = __floats2half2_rn(a2.x, a2.y);
    hh[5] = __floats2half2_rn(a2.z, a2.w);
    hh[6] = __floats2half2_rn(a3.x, a3.y);
    hh[7] = __floats2half2_rn(a3.z, a3.w);
    *(uint4*)&attrC[(size_t)p * 16]     = *(uint4*)&hh[0];
    *(uint4*)&attrC[(size_t)p * 16 + 8] = *(uint4*)&hh[4];
  }
}

// final inverse-permute: coalesced write of out, gather from L2-resident out2
__global__ __launch_bounds__(256) void k_scatter_out(
    const float* __restrict__ out2, const int* __restrict__ pos,
    float* __restrict__ out, int E) {
  int e = blockIdx.x * 256 + threadIdx.x;
  if (e < E) {
    int p = pos[e];
    *(float2*)&out[(size_t)e * 2] = *(const float2*)&out2[(size_t)p * 2];
  }
}

// ---------------- register-blocked node GEMM ----------------
// When stats != nullptr: BN scale/shift computed from 8-way-replicated RAW
// stats sums in an LDS prologue; input transform = relu(x*sc+sh).
template<int K, int MODE>
__global__ __launch_bounds__(256) void k_gemm(
    const float* __restrict__ X, const float* __restrict__ stats,
    const float* __restrict__ gma, const float* __restrict__ bta,
    const float* __restrict__ Wt, const float* __restrict__ bias,
    __half* __restrict__ outH, float* __restrict__ outF, int N, int Ftot) {
  __shared__ __align__(16) float Xs[32][68];
  __shared__ __align__(16) float Ws_[32][128];
  __shared__ float scs[64], shs[64];
  const int tid = threadIdx.x;
  const int tx  = tid & 15;
  const int ty  = tid >> 4;
  const int n0  = blockIdx.x * 64;
  if (stats && tid < 64) {
    float s0 = 0.f, s1 = 0.f;
#pragma unroll
    for (int r = 0; r < 8; ++r) {
      s0 += stats[r * 128 + tid];
      s1 += stats[r * 128 + 64 + tid];
    }
    float inv_n = 1.0f / (float)N;
    float mean = s0 * inv_n;
    float var  = s1 * inv_n - mean * mean;
    float s = gma[tid] * rsqrtf(var + EPS);
    scs[tid] = s;
    shs[tid] = bta[tid] - mean * s;
  }
  float acc[4][8];
#pragma unroll
  for (int j = 0; j < 8; ++j) {
    float bv = bias[8 * tx + j];
#pragma unroll
    for (int i = 0; i < 4; ++i) acc[i][j] = bv;
  }
  for (int k0 = 0; k0 < K; k0 += 32) {
    __syncthreads();
#pragma unroll
    for (int l = 0; l < 2; ++l) {
      int idx = tid * 2 + l;
      int kq = idx & 7, n = idx >> 3;
      float4 xv = make_float4(0.f, 0.f, 0.f, 0.f);
      if (n0 + n < N) xv = *(const float4*)&X[(size_t)(n0 + n) * K + k0 + kq * 4];
      if (stats) {
        int kb = k0 + kq * 4;
        xv.x = fmaxf(xv.x * scs[kb + 0] + shs[kb + 0], 0.f);
        xv.y = fmaxf(xv.y * scs[kb + 1] + shs[kb + 1], 0.f);
        xv.z = fmaxf(xv.z * scs[kb + 2] + shs[kb + 2], 0.f);
        xv.w = fmaxf(xv.w * scs[kb + 3] + shs[kb + 3], 0.f);
      }
      Xs[kq * 4 + 0][n] = xv.x;
      Xs[kq * 4 + 1][n] = xv.y;
      Xs[kq * 4 + 2][n] = xv.z;
      Xs[kq * 4 + 3][n] = xv.w;
    }
#pragma unroll
    for (int l = 0; l < 4; ++l) {
      int idx = tid + l * 256;
      int kr = idx >> 5, fc = idx & 31;
      *(float4*)&Ws_[kr][fc * 4] =
          *(const float4*)&Wt[(size_t)(k0 + kr) * Ftot + fc * 4];
    }
    __syncthreads();
#pragma unroll
    for (int kk = 0; kk < 32; ++kk) {
      float4 a  = *(const float4*)&Xs[kk][4 * ty];
      float4 b0 = *(const float4*)&Ws_[kk][8 * tx];
      float4 b1 = *(const float4*)&Ws_[kk][8 * tx + 4];
      float aa[4] = {a.x, a.y, a.z, a.w};
      float bb[8] = {b0.x, b0.y, b0.z, b0.w, b1.x, b1.y, b1.z, b1.w};
#pragma unroll
      for (int i = 0; i < 4; ++i)
#pragma unroll
        for (int j = 0; j < 8; ++j) acc[i][j] += aa[i] * bb[j];
    }
  }
#pragma unroll
  for (int i = 0; i < 4; ++i) {
    int n = n0 + 4 * ty + i;
    if (n >= N) continue;
    if (tx < 8) {
      __half2 hh[4];
#pragma unroll
      for (int c = 0; c < 4; ++c)
        hh[c] = __floats2half2_rn(acc[i][2 * c], acc[i][2 * c + 1]);
      *(uint4*)&outH[(size_t)n * 64 + 8 * tx] = *(uint4*)hh;
    } else {
      float* cp = outF + (size_t)n * 64 + 8 * tx - 64;
      *(float4*)cp = make_float4(acc[i][0], acc[i][1], acc[i][2], acc[i][3]);
      *(float4*)(cp + 4) = make_float4(acc[i][4], acc[i][5], acc[i][6], acc[i][7]);
    }
  }
}

// ---------------- fused aggregate + mean + residual + BN stats ----------------
// stats is 8-way replicated [8][128]; block b adds into replica b&7.
__global__ __launch_bounds__(256) void k_agg(
    const __half* __restrict__ qb, const float* __restrict__ pb,
    const int* __restrict__ rowptr, const int2* __restrict__ csr_sd,
    float* __restrict__ hpre, float* __restrict__ stats, int N) {
  __shared__ float red[512];
  const int tid  = threadIdx.x;
  const int w    = tid >> 6;
  const int lane = tid & 63;
  const int g    = lane >> 3, c = lane & 7;
  float lsum = 0.f, lsq = 0.f;
  const int wid = blockIdx.x * 4 + w;
  const int nw  = gridDim.x * 4;
  for (int n = wid; n < N; n += nw) {
    const int r0 = rowptr[n], r1 = rowptr[n + 1];
    float s[8] = {0.f, 0.f, 0.f, 0.f, 0.f, 0.f, 0.f, 0.f};
    for (int j = r0 + g; j < r1; j += 8) {
      int a = csr_sd[j].x;
      uint4 rv = *(const uint4*)&qb[(size_t)a * 64 + 8 * c];
      const __half2* hp = (const __half2*)&rv;
#pragma unroll
      for (int q = 0; q < 4; ++q) {
        float2 f2 = __half22float2(hp[q]);
        s[2 * q]     += f2.x;
        s[2 * q + 1] += f2.y;
      }
    }
#pragma unroll
    for (int m = 8; m < 64; m <<= 1)
#pragma unroll
      for (int q = 0; q < 8; ++q) s[q] += __shfl_xor(s[q], m);
    float sv = s[0];
#pragma unroll
    for (int q = 1; q < 8; ++q) sv = (g == q) ? s[q] : sv;
    float cdeg = (float)(r1 - r0);
    cdeg = cdeg > 1.f ? cdeg : 1.f;
    const int f = 8 * c + g;
    float v = sv / cdeg + pb[(size_t)n * 64 + f];
    hpre[(size_t)n * 64 + f] = v;
    lsum += v;
    lsq  += v * v;
  }
  red[tid]       = lsum;
  red[256 + tid] = lsq;
  __syncthreads();
  if (tid < 64) {
    float ts = red[tid] + red[tid + 64] + red[tid + 128] + red[tid + 192];
    float tq = red[256 + tid] + red[256 + tid + 64] + red[256 + tid + 128] + red[256 + tid + 192];
    int f = 8 * (tid & 7) + (tid >> 3);
    float* st = stats + (blockIdx.x & 7) * 128;
    atomicAdd(&st[f], ts);
    atomicAdd(&st[64 + f], tq);
  }
}

// BN2+relu -> fp16 node features h2; scale/shift from 8-way-replicated RAW
// stats (finalize folded into a 64-thread LDS prologue per block).
__global__ __launch_bounds__(256) void k_bn(
    const float* __restrict__ H1, const float* __restrict__ stats,
    const float* __restrict__ g, const float* __restrict__ be,
    __half* __restrict__ H2, int N) {
  __shared__ float scs[64], shs[64];
  const int tid = threadIdx.x;
  if (tid < 64) {
    float s0 = 0.f, s1 = 0.f;
#pragma unroll
    for (int r = 0; r < 8; ++r) {
      s0 += stats[r * 128 + tid];
      s1 += stats[r * 128 + 64 + tid];
    }
    float inv_n = 1.0f / (float)N;
    float mean = s0 * inv_n;
    float var  = s1 * inv_n - mean * mean;
    float s = g[tid] * rsqrtf(var + EPS);
    scs[tid] = s;
    shs[tid] = be[tid] - mean * s;
  }
  __syncthreads();
  int idx = blockIdx.x * 256 + tid;
  if (idx >= N * 8) return;
  int n = idx >> 3, f8 = (idx & 7) * 8;
  float4 h0 = *(const float4*)&H1[(size_t)n * 64 + f8];
  float4 h1 = *(const float4*)&H1[(size_t)n * 64 + f8 + 4];
  __half2 hh[4];
  hh[0] = __floats2half2_rn(fmaxf(h0.x * scs[f8 + 0] + shs[f8 + 0], 0.f),
                            fmaxf(h0.y * scs[f8 + 1] + shs[f8 + 1], 0.f));
  hh[1] = __floats2half2_rn(fmaxf(h0.z * scs[f8 + 2] + shs[f8 + 2], 0.f),
                            fmaxf(h0.w * scs[f8 + 3] + shs[f8 + 3], 0.f));
  hh[2] = __floats2half2_rn(fmaxf(h1.x * scs[f8 + 4] + shs[f8 + 4], 0.f),
                            fmaxf(h1.y * scs[f8 + 5] + shs[f8 + 5], 0.f));
  hh[3] = __floats2half2_rn(fmaxf(h1.z * scs[f8 + 6] + shs[f8 + 6], 0.f),
                            fmaxf(h1.w * scs[f8 + 7] + shs[f8 + 7], 0.f));
  *(uint4*)&H2[(size_t)n * 64 + f8] = *(uint4*)hh;
}

// ---------------------------------------------------------------------------
// Fused edge MLP, all-MFMA, straight-line body, nc-outer layer-1, int2 idx.
// (256,2): VGPR<=128 -> 2 blocks/CU (LDS 74.75KB x2 = 149.5 <= 160 KB).
// ---------------------------------------------------------------------------
__global__ __launch_bounds__(256, 2) void k_edge(
    const __half* __restrict__ H2, const __half* __restrict__ attrC,
    const int2* __restrict__ csd,
    const __half* __restrict__ W1Bws, const __half* __restrict__ W2Bws,
    const float* __restrict__ bm1, const float* __restrict__ bm2,
    const float* __restrict__ Wm3, const float* __restrict__ bm3,
    float* __restrict__ out2, int E) {
  __shared__ __align__(16) _Float16 W1B[20480];
  __shared__ __align__(16) _Float16 W2B[8192];
  __shared__ __align__(16) _Float16 Z1f[64 * 136];

  const int tid  = threadIdx.x;
  const int lane = tid & 63;
  const int w    = tid >> 6;
  const int ln15 = lane & 15;
  const int quad = lane >> 4;

  for (int i = tid; i < 2560; i += 256)
    ((uint4*)W1B)[i] = ((const uint4*)W1Bws)[i];
  for (int i = tid; i < 1024; i += 256)
    ((uint4*)W2B)[i] = ((const uint4*)W2Bws)[i];

  float bm1v[8];
#pragma unroll
  for (int nc = 0; nc < 8; ++nc) bm1v[nc] = bm1[16 * nc + ln15];
  float bmv[4], w30[4], w31[4];
#pragma unroll
  for (int t = 0; t < 4; ++t) {
    bmv[t] = bm2[16 * t + ln15];
    w30[t] = Wm3[16 * t + ln15];
    w31[t] = Wm3[64 + 16 * t + ln15];
  }
  const float bm30 = bm3[0], bm31 = bm3[1];
  __syncthreads();

  const int nt = (E + 63) >> 6;
  const int rowoff = 16 * w + ln15;

  for (int t = blockIdx.x; t < nt; t += gridDim.x) {
    int er = (t << 6) + rowoff;
    if (er >= E) er = E - 1;
    const int2 sd = csd[er];
    const int s = sd.x;
    const int d = sd.y;

    // A-fragments straight from gathers: row = ln15, k-halves = quad*8..+7
    h8 af0 = *(const h8*)&H2[(size_t)s * 64 + 8 * quad];
    h8 af1 = *(const h8*)&H2[(size_t)s * 64 + 32 + 8 * quad];
    h8 af2 = *(const h8*)&H2[(size_t)d * 64 + 8 * quad];
    h8 af3 = *(const h8*)&H2[(size_t)d * 64 + 32 + 8 * quad];
    h8 af4 = (h8){0, 0, 0, 0, 0, 0, 0, 0};
    if (quad < 2)
      af4 = *(const h8*)&attrC[(size_t)er * 16 + 8 * quad];  // coalesced

    // ---- layer 1 (nc outer: each acc retires to Z1f after its 5 MFMAs) ----
    const int ebase = 16 * w + 4 * quad;
#pragma unroll
    for (int nc = 0; nc < 8; ++nc) {
      f32x4 a1 = (f32x4){bm1v[nc], bm1v[nc], bm1v[nc], bm1v[nc]};
      a1 = __builtin_amdgcn_mfma_f32_16x16x32_f16(
          af0, *(const h8*)&W1B[((0 * 8 + nc) << 9) + (lane << 3)], a1, 0, 0, 0);
      a1 = __builtin_amdgcn_mfma_f32_16x16x32_f16(
          af1, *(const h8*)&W1B[((1 * 8 + nc) << 9) + (lane << 3)], a1, 0, 0, 0);
      a1 = __builtin_amdgcn_mfma_f32_16x16x32_f16(
          af2, *(const h8*)&W1B[((2 * 8 + nc) << 9) + (lane << 3)], a1, 0, 0, 0);
      a1 = __builtin_amdgcn_mfma_f32_16x16x32_f16(
          af3, *(const h8*)&W1B[((3 * 8 + nc) << 9) + (lane << 3)], a1, 0, 0, 0);
      a1 = __builtin_amdgcn_mfma_f32_16x16x32_f16(
          af4, *(const h8*)&W1B[((4 * 8 + nc) << 9) + (lane << 3)], a1, 0, 0, 0);
      Z1f[(ebase + 0) * 136 + 16 * nc + ln15] = (_Float16)fmaxf(a1[0], 0.f);
      Z1f[(ebase + 1) * 136 + 16 * nc + ln15] = (_Float16)fmaxf(a1[1], 0.f);
      Z1f[(ebase + 2) * 136 + 16 * nc + ln15] = (_Float16)fmaxf(a1[2], 0.f);
      Z1f[(ebase + 3) * 136 + 16 * nc + ln15] = (_Float16)fmaxf(a1[3], 0.f);
    }

    // ---- layer 2 (wave-local rows; no cross-wave sync needed) ----
    f32x4 acc2[4];
#pragma unroll
    for (int tt = 0; tt < 4; ++tt)
      acc2[tt] = (f32x4){bmv[tt], bmv[tt], bmv[tt], bmv[tt]};
#pragma unroll
    for (int kc = 0; kc < 4; ++kc) {
      h8 a = *(const h8*)&Z1f[(16 * w + ln15) * 136 + 32 * kc + 8 * quad];
#pragma unroll
      for (int tt = 0; tt < 4; ++tt) {
        h8 bf = *(const h8*)&W2B[((kc * 4 + tt) * 64 + lane) * 8];
        acc2[tt] = __builtin_amdgcn_mfma_f32_16x16x32_f16(a, bf, acc2[tt], 0, 0, 0);
      }
    }

    // ---- layer 3 + output (coalesced, CSR order) ----
    float p0[4], p1[4];
#pragma unroll
    for (int r = 0; r < 4; ++r) { p0[r] = 0.f; p1[r] = 0.f; }
#pragma unroll
    for (int tt = 0; tt < 4; ++tt)
#pragma unroll
      for (int r = 0; r < 4; ++r) {
        float z = fmaxf(acc2[tt][r], 0.f);
        p0[r] += z * w30[tt];
        p1[r] += z * w31[tt];
      }
#pragma unroll
    for (int r = 0; r < 4; ++r) {
#pragma unroll
      for (int m = 1; m < 16; m <<= 1) {
        p0[r] += __shfl_xor(p0[r], m);
        p1[r] += __shfl_xor(p1[r], m);
      }
      if (ln15 == 0) {
        int j = (t << 6) + 16 * w + 4 * quad + r;
        if (j < E)
          *(float2*)&out2[(size_t)j * 2] = make_float2(p0[r] + bm30, p1[r] + bm31);
      }
    }
  }
}

extern "C" void kernel_launch(void* const* d_in, const int* in_sizes, int n_in,
                              void* d_out, int out_size, void* d_ws, size_t ws_size,
                              hipStream_t stream) {
  const float* x    = (const float*)d_in[0];
  const int*   ei   = (const int*)d_in[1];
  const float* attr = (const float*)d_in[2];
  const float* W1l  = (const float*)d_in[3];
  const float* b1l  = (const float*)d_in[4];
  const float* W1r  = (const float*)d_in[5];
  const float* g1   = (const float*)d_in[6];
  const float* be1  = (const float*)d_in[7];
  const float* W2l  = (const float*)d_in[8];
  const float* b2l  = (const float*)d_in[9];
  const float* W2r  = (const float*)d_in[10];
  const float* g2   = (const float*)d_in[11];
  const float* be2  = (const float*)d_in[12];
  const float* Wm1  = (const float*)d_in[13];
  const float* bm1  = (const float*)d_in[14];
  const float* Wm2  = (const float*)d_in[15];
  const float* bm2  = (const float*)d_in[16];
  const float* Wm3  = (const float*)d_in[17];
  const float* bm3  = (const float*)d_in[18];
  float* out = (float*)d_out;

  const int N = in_sizes[0] / 128;
  const int E = in_sizes[1] / 2;
  const int* srcI = ei;
  const int* dstI = ei + E;

  float* ws = (float*)d_ws;
  const size_t NF = (size_t)N * 64;
  float*  P32 = ws;                        // [N][64] f32
  float*  H1  = ws + NF;                   // [N][64] f32 (reused as H2pre)
  __half* Q16 = (__half*)(ws + 2 * NF);    // [N][64] f16 (later: H2 table)
  float* small  = ws + 2 * NF + NF / 2;
  float* stats1 = small;          // 8 replicas x 128 = 1024
  float* stats2 = stats1 + 1024;  // 8 replicas x 128 = 1024
  float* Wt1    = stats2 + 1024;  // 128*128
  float* Wt2    = Wt1 + 16384;    // 64*128
  float* bias1  = Wt2 + 8192;     // 128
  float* bias2  = bias1 + 128;    // 128
  __half* W1B   = (__half*)(bias2 + 128);            // 20480 halves = 10240 f
  __half* W2B   = (__half*)(bias2 + 128 + 10240);    // 8192 halves = 4096 f
  int2* csr_sd = (int2*)(bias2 + 128 + 10240 + 4096); // E int2 (8B-aligned)
  int* rowptr = (int*)(csr_sd + E);         // N+1
  int* cursor = rowptr + (N + 1);           // N
  int* deg    = cursor + N;                 // N
  int* pos    = deg + N;                    // E
  __half* attrC = (__half*)(((uintptr_t)(pos + E) + 15) & ~(uintptr_t)15);

  __half* H2  = Q16;   // Q16 dead after 2nd k_agg; k_bn writes H2 there
  float* out2 = H1;    // H1 dead after k_bn reads it

  hipMemsetAsync(deg, 0, (size_t)N * sizeof(int), stream);
  hipMemsetAsync(stats1, 0, 2048 * sizeof(float), stream);

  // ---- weight prep + degree histogram (one launch) ----
  const int eBlocks = (E + 255) / 256;
  const int prepBlocks = (53504 + 255) / 256;
  k_prep_hist<<<prepBlocks + eBlocks, 256, 0, stream>>>(
      W1l, W1r, b1l, W2l, W2r, b2l, Wm1, Wm2,
      Wt1, Wt2, bias1, bias2, W2B, W1B,
      dstI, deg, E, prepBlocks);
  k_scan<<<1, 1024, 0, stream>>>(deg, rowptr, cursor, N);
  k_fill<<<eBlocks, 256, 0, stream>>>(srcI, dstI, attr, cursor,
                                      csr_sd, pos, attrC, E);

  const int mTiles = (N + 63) / 64;

  // ---- conv1: Q16 = fp16(x@W1l^T), P32 = x@W1r^T + b1l ----
  k_gemm<128, 0><<<mTiles, 256, 0, stream>>>(x, nullptr, nullptr, nullptr,
                                             Wt1, bias1, Q16, P32, N, 128);
  k_agg<<<1024, 256, 0, stream>>>(Q16, P32, rowptr, csr_sd, H1, stats1, N);

  // ---- conv2 (BN1+relu computed from replicated raw stats in-gemm) ----
  k_gemm<64, 0><<<mTiles, 256, 0, stream>>>(H1, stats1, g1, be1,
                                            Wt2, bias2, Q16, P32, N, 128);
  k_agg<<<1024, 256, 0, stream>>>(Q16, P32, rowptr, csr_sd, H1, stats2, N);

  // ---- BN2+relu -> fp16 h2 table (finalize folded in) ----
  k_bn<<<(N * 8 + 255) / 256, 256, 0, stream>>>(H1, stats2, g2, be2, H2, N);

  // ---- fused all-MFMA edge MLP over dst-CSR edges, coalesced out2 ----
  k_edge<<<1024, 256, 0, stream>>>(H2, attrC, csr_sd,
                                   W1B, W2B, bm1, bm2, Wm3, bm3, out2, E);
  // ---- inverse-permute to final output order ----
  k_scatter_out<<<eBlocks, 256, 0, stream>>>(out2, pos, out, E);
}

// Round 14
// 484.729 us; speedup vs baseline: 1.1639x; 1.0170x over previous
//
#include <hip/hip_runtime.h>
#include <hip/hip_fp16.h>

// ---------------------------------------------------------------------------
// EdgeClassifierGNN: 2x SAGEConv(mean)+BN+ReLU, then 3-layer edge MLP.
// Trick 1: lin_l before mean-aggregation (64-wide gather).
// Trick 3: CSR by dst -> atomic-free aggregation; k_edge in dst order.
// Trick 4: node linears via register-blocked GEMM, BN fused on input.
// Trick 6: k_edge layer 2 via v_mfma_f32_16x16x32_f16 + shfl epilogue.
// Trick 7 (r9): k_agg wave-per-node with 8-edges-per-load gather + butterfly.
// Trick 10 (r12): k_edge layer 1 ALSO via MFMA on gathered 64-dim fp16 node
//          features (single 6.4 MB table, A-frags straight from the loads).
// Trick 12 (r17): attr pre-gathered to CSR order as fp16 (attrC) in k_fill.
// Trick 13 (r19): nc-outer layer-1 -> acc retires per-nc; (256,2) spill-free.
// Trick 14 (r20): csr (src,dst) packed int2; k_finalize folded into prologues.
// Trick 16 (r22): replicated stats accumulators kill the same-address atomic
//          tail (r13: 8-way -71us); r14: 32-way (chain 128->32).
// Trick 17 (r23): k_edge EDGE-PAIRING — each wave handles 32 edges (two
//          16-row groups) so every W1B/W2B fragment read feeds 2 MFMAs:
//          ds_read_b128/edge 3.5 -> 1.5. Counter math (m134, 12cyc/b128):
//          old 56 reads x 50k wave-tiles = 33.6M cyc /256CU = 62us = ~70% of
//          k_edge's 90us -> LDS-read issue WAS the critical path. Tile=128
//          edges; Z1f 128x136 (34.8KB); W2B reads moved to GLOBAL (16KB
//          L2-hot table) so LDS = 75.8KB keeps 2 blocks/CU.
// ---------------------------------------------------------------------------

#define EPS 1e-5f

typedef _Float16 h8 __attribute__((ext_vector_type(8)));
typedef float f32x4 __attribute__((ext_vector_type(4)));

// ---------------- CSR build + weight prep (merged) ----------------
// prep elements: Wt1 16384 | Wt2 8192 | bias1 128 | bias2 128 | W2B 8192 |
//                W1B 20480  => 53504 total
__global__ __launch_bounds__(256) void k_prep_hist(
    const float* __restrict__ W1l, const float* __restrict__ W1r,
    const float* __restrict__ b1l,
    const float* __restrict__ W2l, const float* __restrict__ W2r,
    const float* __restrict__ b2l,
    const float* __restrict__ Wm1, const float* __restrict__ Wm2,
    float* __restrict__ Wt1, float* __restrict__ Wt2,
    float* __restrict__ bias1, float* __restrict__ bias2,
    __half* __restrict__ W2B, __half* __restrict__ W1B,
    const int* __restrict__ dst, int* __restrict__ deg, int E, int prepBlocks) {
  if ((int)blockIdx.x >= prepBlocks) {
    int e = (blockIdx.x - prepBlocks) * 256 + threadIdx.x;
    if (e < E) atomicAdd(&deg[dst[e]], 1);
    return;
  }
  int idx = blockIdx.x * 256 + threadIdx.x;
  if (idx < 16384) {  // Wt1 [128k x 128f] = [W1l | W1r]^T
    int k = idx >> 7, f = idx & 127;
    Wt1[idx] = (f < 64) ? W1l[f * 128 + k] : W1r[(f - 64) * 128 + k];
    return;
  }
  idx -= 16384;
  if (idx < 8192) {   // Wt2 [64k x 128f] = [W2l | W2r]^T
    int k = idx >> 7, f = idx & 127;
    Wt2[idx] = (f < 64) ? W2l[f * 64 + k] : W2r[(f - 64) * 64 + k];
    return;
  }
  idx -= 8192;
  if (idx < 128) { bias1[idx] = (idx < 64) ? 0.f : b1l[idx - 64]; return; }
  idx -= 128;
  if (idx < 128) { bias2[idx] = (idx < 64) ? 0.f : b2l[idx - 64]; return; }
  idx -= 128;
  if (idx < 8192) {   // W2B: Wm2^T pre-swizzled to MFMA B-fragment layout
    int j = idx & 7, l = (idx >> 3) & 63, f = idx >> 9;
    int kc = f >> 2, tt = f & 3;
    int col = 16 * tt + (l & 15);
    int k = 32 * kc + (l >> 4) * 8 + j;
    W2B[idx] = __float2half(Wm2[col * 128 + k]);
    return;
  }
  idx -= 8192;
  if (idx < 20480) {  // W1B: layer-1 Wcat (160x128) in MFMA B-fragment layout
    int j = idx & 7, l = (idx >> 3) & 63, f = idx >> 9;  // f = kc*8+nc, 0..39
    int kc = f >> 3, nc = f & 7;
    int k = 32 * kc + (l >> 4) * 8 + j;   // 0..159
    int n = 16 * nc + (l & 15);           // 0..127
    float w;
    if (k < 64)       w = Wm1[n * 144 + k];            // src cols 0..63
    else if (k < 128) w = Wm1[n * 144 + 80 + (k - 64)];// dst cols 80..143
    else if (k < 144) w = Wm1[n * 144 + 64 + (k - 128)];// attr cols 64..79
    else              w = 0.f;                          // pad
    W1B[idx] = __float2half(w);
    return;
  }
}

__global__ __launch_bounds__(1024) void k_scan(
    const int* __restrict__ deg, int* __restrict__ rowptr,
    int* __restrict__ cursor, int N) {
  __shared__ int wsum[16];
  __shared__ int carry;
  const int lane = threadIdx.x & 63;
  const int w    = threadIdx.x >> 6;
  if (threadIdx.x == 0) carry = 0;
  __syncthreads();
  for (int base = 0; base < N; base += 1024) {
    int i = base + threadIdx.x;
    int v = (i < N) ? deg[i] : 0;
    int incl = v;
#pragma unroll
    for (int off = 1; off < 64; off <<= 1) {
      int t = __shfl_up(incl, off);
      if (lane >= off) incl += t;
    }
    if (lane == 63) wsum[w] = incl;
    __syncthreads();
    if (w == 0) {
      int ws_ = (lane < 16) ? wsum[lane] : 0;
      int wincl = ws_;
#pragma unroll
      for (int off = 1; off < 16; off <<= 1) {
        int t = __shfl_up(wincl, off);
        if (lane >= off) wincl += t;
      }
      if (lane < 16) wsum[lane] = wincl;
    }
    __syncthreads();
    int woff = carry + (w > 0 ? wsum[w - 1] : 0);
    int excl = woff + incl - v;
    if (i < N) { rowptr[i] = excl; cursor[i] = excl; }
    int tot = wsum[15];
    __syncthreads();
    if (threadIdx.x == 0) carry += tot;
    __syncthreads();
  }
  if (threadIdx.x == 0) rowptr[N] = carry;
}

// CSR scatter (packed int2); records pos[eid]; pre-gathers attr as fp16.
__global__ __launch_bounds__(256) void k_fill(
    const int* __restrict__ src, const int* __restrict__ dst,
    const float* __restrict__ attr,
    int* __restrict__ cursor, int2* __restrict__ csr_sd,
    int* __restrict__ pos, __half* __restrict__ attrC, int E) {
  int e = blockIdx.x * 256 + threadIdx.x;
  if (e < E) {
    int d = dst[e];
    int p = atomicAdd(&cursor[d], 1);
    csr_sd[p] = make_int2(src[e], d);
    pos[e] = p;
    const float4* at4 = (const float4*)attr;
    float4 a0 = at4[(size_t)e * 4 + 0];
    float4 a1 = at4[(size_t)e * 4 + 1];
    float4 a2 = at4[(size_t)e * 4 + 2];
    float4 a3 = at4[(size_t)e * 4 + 3];
    __half2 hh[8];
    hh[0] = __floats2half2_rn(a0.x, a0.y);
    hh[1] = __floats2half2_rn(a0.z, a0.w);
    hh[2] = __floats2half2_rn(a1.x, a1.y);
    hh[3] = __floats2half2_rn(a1.z, a1.w);
    hh[4] = __floats2half2_rn(a2.x, a2.y);
    hh[5] = __floats2half2_rn(a2.z, a2.w);
    hh[6] = __floats2half2_rn(a3.x, a3.y);
    hh[7] = __floats2half2_rn(a3.z, a3.w);
    *(uint4*)&attrC[(size_t)p * 16]     = *(uint4*)&hh[0];
    *(uint4*)&attrC[(size_t)p * 16 + 8] = *(uint4*)&hh[4];
  }
}

// final inverse-permute: coalesced write of out, gather from L2-resident out2
__global__ __launch_bounds__(256) void k_scatter_out(
    const float* __restrict__ out2, const int* __restrict__ pos,
    float* __restrict__ out, int E) {
  int e = blockIdx.x * 256 + threadIdx.x;
  if (e < E) {
    int p = pos[e];
    *(float2*)&out[(size_t)e * 2] = *(const float2*)&out2[(size_t)p * 2];
  }
}

// ---------------- register-blocked node GEMM ----------------
// When stats != nullptr: BN scale/shift computed from 32-way-replicated RAW
// stats sums in an LDS prologue; input transform = relu(x*sc+sh).
template<int K, int MODE>
__global__ __launch_bounds__(256) void k_gemm(
    const float* __restrict__ X, const float* __restrict__ stats,
    const float* __restrict__ gma, const float* __restrict__ bta,
    const float* __restrict__ Wt, const float* __restrict__ bias,
    __half* __restrict__ outH, float* __restrict__ outF, int N, int Ftot) {
  __shared__ __align__(16) float Xs[32][68];
  __shared__ __align__(16) float Ws_[32][128];
  __shared__ float scs[64], shs[64];
  const int tid = threadIdx.x;
  const int tx  = tid & 15;
  const int ty  = tid >> 4;
  const int n0  = blockIdx.x * 64;
  if (stats && tid < 64) {
    float s0 = 0.f, s1 = 0.f;
#pragma unroll
    for (int r = 0; r < 32; ++r) {
      s0 += stats[r * 128 + tid];
      s1 += stats[r * 128 + 64 + tid];
    }
    float inv_n = 1.0f / (float)N;
    float mean = s0 * inv_n;
    float var  = s1 * inv_n - mean * mean;
    float s = gma[tid] * rsqrtf(var + EPS);
    scs[tid] = s;
    shs[tid] = bta[tid] - mean * s;
  }
  float acc[4][8];
#pragma unroll
  for (int j = 0; j < 8; ++j) {
    float bv = bias[8 * tx + j];
#pragma unroll
    for (int i = 0; i < 4; ++i) acc[i][j] = bv;
  }
  for (int k0 = 0; k0 < K; k0 += 32) {
    __syncthreads();
#pragma unroll
    for (int l = 0; l < 2; ++l) {
      int idx = tid * 2 + l;
      int kq = idx & 7, n = idx >> 3;
      float4 xv = make_float4(0.f, 0.f, 0.f, 0.f);
      if (n0 + n < N) xv = *(const float4*)&X[(size_t)(n0 + n) * K + k0 + kq * 4];
      if (stats) {
        int kb = k0 + kq * 4;
        xv.x = fmaxf(xv.x * scs[kb + 0] + shs[kb + 0], 0.f);
        xv.y = fmaxf(xv.y * scs[kb + 1] + shs[kb + 1], 0.f);
        xv.z = fmaxf(xv.z * scs[kb + 2] + shs[kb + 2], 0.f);
        xv.w = fmaxf(xv.w * scs[kb + 3] + shs[kb + 3], 0.f);
      }
      Xs[kq * 4 + 0][n] = xv.x;
      Xs[kq * 4 + 1][n] = xv.y;
      Xs[kq * 4 + 2][n] = xv.z;
      Xs[kq * 4 + 3][n] = xv.w;
    }
#pragma unroll
    for (int l = 0; l < 4; ++l) {
      int idx = tid + l * 256;
      int kr = idx >> 5, fc = idx & 31;
      *(float4*)&Ws_[kr][fc * 4] =
          *(const float4*)&Wt[(size_t)(k0 + kr) * Ftot + fc * 4];
    }
    __syncthreads();
#pragma unroll
    for (int kk = 0; kk < 32; ++kk) {
      float4 a  = *(const float4*)&Xs[kk][4 * ty];
      float4 b0 = *(const float4*)&Ws_[kk][8 * tx];
      float4 b1 = *(const float4*)&Ws_[kk][8 * tx + 4];
      float aa[4] = {a.x, a.y, a.z, a.w};
      float bb[8] = {b0.x, b0.y, b0.z, b0.w, b1.x, b1.y, b1.z, b1.w};
#pragma unroll
      for (int i = 0; i < 4; ++i)
#pragma unroll
        for (int j = 0; j < 8; ++j) acc[i][j] += aa[i] * bb[j];
    }
  }
#pragma unroll
  for (int i = 0; i < 4; ++i) {
    int n = n0 + 4 * ty + i;
    if (n >= N) continue;
    if (tx < 8) {
      __half2 hh[4];
#pragma unroll
      for (int c = 0; c < 4; ++c)
        hh[c] = __floats2half2_rn(acc[i][2 * c], acc[i][2 * c + 1]);
      *(uint4*)&outH[(size_t)n * 64 + 8 * tx] = *(uint4*)hh;
    } else {
      float* cp = outF + (size_t)n * 64 + 8 * tx - 64;
      *(float4*)cp = make_float4(acc[i][0], acc[i][1], acc[i][2], acc[i][3]);
      *(float4*)(cp + 4) = make_float4(acc[i][4], acc[i][5], acc[i][6], acc[i][7]);
    }
  }
}

// ---------------- fused aggregate + mean + residual + BN stats ----------------
// stats is 32-way replicated [32][128]; block b adds into replica b&31.
__global__ __launch_bounds__(256) void k_agg(
    const __half* __restrict__ qb, const float* __restrict__ pb,
    const int* __restrict__ rowptr, const int2* __restrict__ csr_sd,
    float* __restrict__ hpre, float* __restrict__ stats, int N) {
  __shared__ float red[512];
  const int tid  = threadIdx.x;
  const int w    = tid >> 6;
  const int lane = tid & 63;
  const int g    = lane >> 3, c = lane & 7;
  float lsum = 0.f, lsq = 0.f;
  const int wid = blockIdx.x * 4 + w;
  const int nw  = gridDim.x * 4;
  for (int n = wid; n < N; n += nw) {
    const int r0 = rowptr[n], r1 = rowptr[n + 1];
    float s[8] = {0.f, 0.f, 0.f, 0.f, 0.f, 0.f, 0.f, 0.f};
    for (int j = r0 + g; j < r1; j += 8) {
      int a = csr_sd[j].x;
      uint4 rv = *(const uint4*)&qb[(size_t)a * 64 + 8 * c];
      const __half2* hp = (const __half2*)&rv;
#pragma unroll
      for (int q = 0; q < 4; ++q) {
        float2 f2 = __half22float2(hp[q]);
        s[2 * q]     += f2.x;
        s[2 * q + 1] += f2.y;
      }
    }
#pragma unroll
    for (int m = 8; m < 64; m <<= 1)
#pragma unroll
      for (int q = 0; q < 8; ++q) s[q] += __shfl_xor(s[q], m);
    float sv = s[0];
#pragma unroll
    for (int q = 1; q < 8; ++q) sv = (g == q) ? s[q] : sv;
    float cdeg = (float)(r1 - r0);
    cdeg = cdeg > 1.f ? cdeg : 1.f;
    const int f = 8 * c + g;
    float v = sv / cdeg + pb[(size_t)n * 64 + f];
    hpre[(size_t)n * 64 + f] = v;
    lsum += v;
    lsq  += v * v;
  }
  red[tid]       = lsum;
  red[256 + tid] = lsq;
  __syncthreads();
  if (tid < 64) {
    float ts = red[tid] + red[tid + 64] + red[tid + 128] + red[tid + 192];
    float tq = red[256 + tid] + red[256 + tid + 64] + red[256 + tid + 128] + red[256 + tid + 192];
    int f = 8 * (tid & 7) + (tid >> 3);
    float* st = stats + (blockIdx.x & 31) * 128;
    atomicAdd(&st[f], ts);
    atomicAdd(&st[64 + f], tq);
  }
}

// BN2+relu -> fp16 node features h2; scale/shift from 32-way-replicated RAW
// stats (finalize folded into a 64-thread LDS prologue per block).
__global__ __launch_bounds__(256) void k_bn(
    const float* __restrict__ H1, const float* __restrict__ stats,
    const float* __restrict__ g, const float* __restrict__ be,
    __half* __restrict__ H2, int N) {
  __shared__ float scs[64], shs[64];
  const int tid = threadIdx.x;
  if (tid < 64) {
    float s0 = 0.f, s1 = 0.f;
#pragma unroll
    for (int r = 0; r < 32; ++r) {
      s0 += stats[r * 128 + tid];
      s1 += stats[r * 128 + 64 + tid];
    }
    float inv_n = 1.0f / (float)N;
    float mean = s0 * inv_n;
    float var  = s1 * inv_n - mean * mean;
    float s = g[tid] * rsqrtf(var + EPS);
    scs[tid] = s;
    shs[tid] = be[tid] - mean * s;
  }
  __syncthreads();
  int idx = blockIdx.x * 256 + tid;
  if (idx >= N * 8) return;
  int n = idx >> 3, f8 = (idx & 7) * 8;
  float4 h0 = *(const float4*)&H1[(size_t)n * 64 + f8];
  float4 h1 = *(const float4*)&H1[(size_t)n * 64 + f8 + 4];
  __half2 hh[4];
  hh[0] = __floats2half2_rn(fmaxf(h0.x * scs[f8 + 0] + shs[f8 + 0], 0.f),
                            fmaxf(h0.y * scs[f8 + 1] + shs[f8 + 1], 0.f));
  hh[1] = __floats2half2_rn(fmaxf(h0.z * scs[f8 + 2] + shs[f8 + 2], 0.f),
                            fmaxf(h0.w * scs[f8 + 3] + shs[f8 + 3], 0.f));
  hh[2] = __floats2half2_rn(fmaxf(h1.x * scs[f8 + 4] + shs[f8 + 4], 0.f),
                            fmaxf(h1.y * scs[f8 + 5] + shs[f8 + 5], 0.f));
  hh[3] = __floats2half2_rn(fmaxf(h1.z * scs[f8 + 6] + shs[f8 + 6], 0.f),
                            fmaxf(h1.w * scs[f8 + 7] + shs[f8 + 7], 0.f));
  *(uint4*)&H2[(size_t)n * 64 + f8] = *(uint4*)hh;
}

// ---------------------------------------------------------------------------
// Fused edge MLP, all-MFMA, EDGE-PAIRED: tile = 128 edges, each wave owns 32
// (two 16-row groups A/B) so every B-fragment read feeds 2 MFMAs.
// W1B in LDS (40KB); W2B read from GLOBAL (16KB, L2-hot); Z1f 128x136 fp16.
// LDS 75.8KB -> 2 blocks/CU at VGPR<=128.
// ---------------------------------------------------------------------------
__global__ __launch_bounds__(256, 2) void k_edge(
    const __half* __restrict__ H2, const __half* __restrict__ attrC,
    const int2* __restrict__ csd,
    const __half* __restrict__ W1Bws, const __half* __restrict__ W2Bws,
    const float* __restrict__ bm1, const float* __restrict__ bm2,
    const float* __restrict__ Wm3, const float* __restrict__ bm3,
    float* __restrict__ out2, int E) {
  __shared__ __align__(16) _Float16 W1B[20480];
  __shared__ __align__(16) _Float16 Z1f[128 * 136];

  const int tid  = threadIdx.x;
  const int lane = tid & 63;
  const int w    = tid >> 6;
  const int ln15 = lane & 15;
  const int quad = lane >> 4;

  for (int i = tid; i < 2560; i += 256)
    ((uint4*)W1B)[i] = ((const uint4*)W1Bws)[i];

  float bm1v[8];
#pragma unroll
  for (int nc = 0; nc < 8; ++nc) bm1v[nc] = bm1[16 * nc + ln15];
  float bmv[4], w30[4], w31[4];
#pragma unroll
  for (int t = 0; t < 4; ++t) {
    bmv[t] = bm2[16 * t + ln15];
    w30[t] = Wm3[16 * t + ln15];
    w31[t] = Wm3[64 + 16 * t + ln15];
  }
  const float bm30 = bm3[0], bm31 = bm3[1];
  __syncthreads();

  const int nt = (E + 127) >> 7;
  const int rowA = 32 * w + ln15;        // group A edge row within tile
  const int rowB = 32 * w + 16 + ln15;   // group B

  for (int t = blockIdx.x; t < nt; t += gridDim.x) {
    const int e0 = t << 7;
    int erA = e0 + rowA; if (erA >= E) erA = E - 1;
    int erB = e0 + rowB; if (erB >= E) erB = E - 1;
    const int2 sdA = csd[erA];
    const int2 sdB = csd[erB];

    // A-fragments (row = ln15 within group, k-halves = quad*8..+7)
    h8 aA0 = *(const h8*)&H2[(size_t)sdA.x * 64 + 8 * quad];
    h8 aA1 = *(const h8*)&H2[(size_t)sdA.x * 64 + 32 + 8 * quad];
    h8 aA2 = *(const h8*)&H2[(size_t)sdA.y * 64 + 8 * quad];
    h8 aA3 = *(const h8*)&H2[(size_t)sdA.y * 64 + 32 + 8 * quad];
    h8 aB0 = *(const h8*)&H2[(size_t)sdB.x * 64 + 8 * quad];
    h8 aB1 = *(const h8*)&H2[(size_t)sdB.x * 64 + 32 + 8 * quad];
    h8 aB2 = *(const h8*)&H2[(size_t)sdB.y * 64 + 8 * quad];
    h8 aB3 = *(const h8*)&H2[(size_t)sdB.y * 64 + 32 + 8 * quad];
    h8 aA4 = (h8){0, 0, 0, 0, 0, 0, 0, 0};
    h8 aB4 = (h8){0, 0, 0, 0, 0, 0, 0, 0};
    if (quad < 2) {
      aA4 = *(const h8*)&attrC[(size_t)erA * 16 + 8 * quad];
      aB4 = *(const h8*)&attrC[(size_t)erB * 16 + 8 * quad];
    }

    // ---- layer 1 (nc outer; each B-frag read feeds both groups) ----
    const int ebA = 32 * w + 4 * quad;
    const int ebB = 32 * w + 16 + 4 * quad;
#pragma unroll
    for (int nc = 0; nc < 8; ++nc) {
      f32x4 cA = (f32x4){bm1v[nc], bm1v[nc], bm1v[nc], bm1v[nc]};
      f32x4 cB = cA;
      h8 bf;
      bf = *(const h8*)&W1B[((0 * 8 + nc) << 9) + (lane << 3)];
      cA = __builtin_amdgcn_mfma_f32_16x16x32_f16(aA0, bf, cA, 0, 0, 0);
      cB = __builtin_amdgcn_mfma_f32_16x16x32_f16(aB0, bf, cB, 0, 0, 0);
      bf = *(const h8*)&W1B[((1 * 8 + nc) << 9) + (lane << 3)];
      cA = __builtin_amdgcn_mfma_f32_16x16x32_f16(aA1, bf, cA, 0, 0, 0);
      cB = __builtin_amdgcn_mfma_f32_16x16x32_f16(aB1, bf, cB, 0, 0, 0);
      bf = *(const h8*)&W1B[((2 * 8 + nc) << 9) + (lane << 3)];
      cA = __builtin_amdgcn_mfma_f32_16x16x32_f16(aA2, bf, cA, 0, 0, 0);
      cB = __builtin_amdgcn_mfma_f32_16x16x32_f16(aB2, bf, cB, 0, 0, 0);
      bf = *(const h8*)&W1B[((3 * 8 + nc) << 9) + (lane << 3)];
      cA = __builtin_amdgcn_mfma_f32_16x16x32_f16(aA3, bf, cA, 0, 0, 0);
      cB = __builtin_amdgcn_mfma_f32_16x16x32_f16(aB3, bf, cB, 0, 0, 0);
      bf = *(const h8*)&W1B[((4 * 8 + nc) << 9) + (lane << 3)];
      cA = __builtin_amdgcn_mfma_f32_16x16x32_f16(aA4, bf, cA, 0, 0, 0);
      cB = __builtin_amdgcn_mfma_f32_16x16x32_f16(aB4, bf, cB, 0, 0, 0);
      Z1f[(ebA + 0) * 136 + 16 * nc + ln15] = (_Float16)fmaxf(cA[0], 0.f);
      Z1f[(ebA + 1) * 136 + 16 * nc + ln15] = (_Float16)fmaxf(cA[1], 0.f);
      Z1f[(ebA + 2) * 136 + 16 * nc + ln15] = (_Float16)fmaxf(cA[2], 0.f);
      Z1f[(ebA + 3) * 136 + 16 * nc + ln15] = (_Float16)fmaxf(cA[3], 0.f);
      Z1f[(ebB + 0) * 136 + 16 * nc + ln15] = (_Float16)fmaxf(cB[0], 0.f);
      Z1f[(ebB + 1) * 136 + 16 * nc + ln15] = (_Float16)fmaxf(cB[1], 0.f);
      Z1f[(ebB + 2) * 136 + 16 * nc + ln15] = (_Float16)fmaxf(cB[2], 0.f);
      Z1f[(ebB + 3) * 136 + 16 * nc + ln15] = (_Float16)fmaxf(cB[3], 0.f);
    }

    // ---- layer 2 (wave-local rows; B-frags from GLOBAL, shared A/B) ----
    f32x4 c2A[4], c2B[4];
#pragma unroll
    for (int tt = 0; tt < 4; ++tt) {
      c2A[tt] = (f32x4){bmv[tt], bmv[tt], bmv[tt], bmv[tt]};
      c2B[tt] = c2A[tt];
    }
#pragma unroll
    for (int kc = 0; kc < 4; ++kc) {
      h8 zA = *(const h8*)&Z1f[(32 * w + ln15) * 136 + 32 * kc + 8 * quad];
      h8 zB = *(const h8*)&Z1f[(32 * w + 16 + ln15) * 136 + 32 * kc + 8 * quad];
#pragma unroll
      for (int tt = 0; tt < 4; ++tt) {
        h8 bf = *(const h8*)&W2Bws[((kc * 4 + tt) * 64 + lane) * 8];
        c2A[tt] = __builtin_amdgcn_mfma_f32_16x16x32_f16(zA, bf, c2A[tt], 0, 0, 0);
        c2B[tt] = __builtin_amdgcn_mfma_f32_16x16x32_f16(zB, bf, c2B[tt], 0, 0, 0);
      }
    }

    // ---- layer 3 + output, group A then group B (coalesced, CSR order) ----
    {
      float p0[4], p1[4];
#pragma unroll
      for (int r = 0; r < 4; ++r) { p0[r] = 0.f; p1[r] = 0.f; }
#pragma unroll
      for (int tt = 0; tt < 4; ++tt)
#pragma unroll
        for (int r = 0; r < 4; ++r) {
          float z = fmaxf(c2A[tt][r], 0.f);
          p0[r] += z * w30[tt];
          p1[r] += z * w31[tt];
        }
#pragma unroll
      for (int r = 0; r < 4; ++r) {
#pragma unroll
        for (int m = 1; m < 16; m <<= 1) {
          p0[r] += __shfl_xor(p0[r], m);
          p1[r] += __shfl_xor(p1[r], m);
        }
        if (ln15 == 0) {
          int j = e0 + 32 * w + 4 * quad + r;
          if (j < E)
            *(float2*)&out2[(size_t)j * 2] = make_float2(p0[r] + bm30, p1[r] + bm31);
        }
      }
    }
    {
      float p0[4], p1[4];
#pragma unroll
      for (int r = 0; r < 4; ++r) { p0[r] = 0.f; p1[r] = 0.f; }
#pragma unroll
      for (int tt = 0; tt < 4; ++tt)
#pragma unroll
        for (int r = 0; r < 4; ++r) {
          float z = fmaxf(c2B[tt][r], 0.f);
          p0[r] += z * w30[tt];
          p1[r] += z * w31[tt];
        }
#pragma unroll
      for (int r = 0; r < 4; ++r) {
#pragma unroll
        for (int m = 1; m < 16; m <<= 1) {
          p0[r] += __shfl_xor(p0[r], m);
          p1[r] += __shfl_xor(p1[r], m);
        }
        if (ln15 == 0) {
          int j = e0 + 32 * w + 16 + 4 * quad + r;
          if (j < E)
            *(float2*)&out2[(size_t)j * 2] = make_float2(p0[r] + bm30, p1[r] + bm31);
        }
      }
    }
  }
}

extern "C" void kernel_launch(void* const* d_in, const int* in_sizes, int n_in,
                              void* d_out, int out_size, void* d_ws, size_t ws_size,
                              hipStream_t stream) {
  const float* x    = (const float*)d_in[0];
  const int*   ei   = (const int*)d_in[1];
  const float* attr = (const float*)d_in[2];
  const float* W1l  = (const float*)d_in[3];
  const float* b1l  = (const float*)d_in[4];
  const float* W1r  = (const float*)d_in[5];
  const float* g1   = (const float*)d_in[6];
  const float* be1  = (const float*)d_in[7];
  const float* W2l  = (const float*)d_in[8];
  const float* b2l  = (const float*)d_in[9];
  const float* W2r  = (const float*)d_in[10];
  const float* g2   = (const float*)d_in[11];
  const float* be2  = (const float*)d_in[12];
  const float* Wm1  = (const float*)d_in[13];
  const float* bm1  = (const float*)d_in[14];
  const float* Wm2  = (const float*)d_in[15];
  const float* bm2  = (const float*)d_in[16];
  const float* Wm3  = (const float*)d_in[17];
  const float* bm3  = (const float*)d_in[18];
  float* out = (float*)d_out;

  const int N = in_sizes[0] / 128;
  const int E = in_sizes[1] / 2;
  const int* srcI = ei;
  const int* dstI = ei + E;

  float* ws = (float*)d_ws;
  const size_t NF = (size_t)N * 64;
  float*  P32 = ws;                        // [N][64] f32
  float*  H1  = ws + NF;                   // [N][64] f32 (reused as H2pre)
  __half* Q16 = (__half*)(ws + 2 * NF);    // [N][64] f16 (later: H2 table)
  float* small  = ws + 2 * NF + NF / 2;
  float* stats1 = small;          // 32 replicas x 128 = 4096
  float* stats2 = stats1 + 4096;  // 32 replicas x 128 = 4096
  float* Wt1    = stats2 + 4096;  // 128*128
  float* Wt2    = Wt1 + 16384;    // 64*128
  float* bias1  = Wt2 + 8192;     // 128
  float* bias2  = bias1 + 128;    // 128
  __half* W1B   = (__half*)(bias2 + 128);            // 20480 halves = 10240 f
  __half* W2B   = (__half*)(bias2 + 128 + 10240);    // 8192 halves = 4096 f
  int2* csr_sd = (int2*)(bias2 + 128 + 10240 + 4096); // E int2 (8B-aligned)
  int* rowptr = (int*)(csr_sd + E);         // N+1
  int* cursor = rowptr + (N + 1);           // N
  int* deg    = cursor + N;                 // N
  int* pos    = deg + N;                    // E
  __half* attrC = (__half*)(((uintptr_t)(pos + E) + 15) & ~(uintptr_t)15);

  __half* H2  = Q16;   // Q16 dead after 2nd k_agg; k_bn writes H2 there
  float* out2 = H1;    // H1 dead after k_bn reads it

  hipMemsetAsync(deg, 0, (size_t)N * sizeof(int), stream);
  hipMemsetAsync(stats1, 0, 8192 * sizeof(float), stream);

  // ---- weight prep + degree histogram (one launch) ----
  const int eBlocks = (E + 255) / 256;
  const int prepBlocks = (53504 + 255) / 256;
  k_prep_hist<<<prepBlocks + eBlocks, 256, 0, stream>>>(
      W1l, W1r, b1l, W2l, W2r, b2l, Wm1, Wm2,
      Wt1, Wt2, bias1, bias2, W2B, W1B,
      dstI, deg, E, prepBlocks);
  k_scan<<<1, 1024, 0, stream>>>(deg, rowptr, cursor, N);
  k_fill<<<eBlocks, 256, 0, stream>>>(srcI, dstI, attr, cursor,
                                      csr_sd, pos, attrC, E);

  const int mTiles = (N + 63) / 64;

  // ---- conv1: Q16 = fp16(x@W1l^T), P32 = x@W1r^T + b1l ----
  k_gemm<128, 0><<<mTiles, 256, 0, stream>>>(x, nullptr, nullptr, nullptr,
                                             Wt1, bias1, Q16, P32, N, 128);
  k_agg<<<1024, 256, 0, stream>>>(Q16, P32, rowptr, csr_sd, H1, stats1, N);

  // ---- conv2 (BN1+relu computed from replicated raw stats in-gemm) ----
  k_gemm<64, 0><<<mTiles, 256, 0, stream>>>(H1, stats1, g1, be1,
                                            Wt2, bias2, Q16, P32, N, 128);
  k_agg<<<1024, 256, 0, stream>>>(Q16, P32, rowptr, csr_sd, H1, stats2, N);

  // ---- BN2+relu -> fp16 h2 table (finalize folded in) ----
  k_bn<<<(N * 8 + 255) / 256, 256, 0, stream>>>(H1, stats2, g2, be2, H2, N);

  // ---- fused all-MFMA edge MLP (edge-paired), coalesced out2 ----
  k_edge<<<1024, 256, 0, stream>>>(H2, attrC, csr_sd,
                                   W1B, W2B, bm1, bm2, Wm3, bm3, out2, E);
  // ---- inverse-permute to final output order ----
  k_scatter_out<<<eBlocks, 256, 0, stream>>>(out2, pos, out, E);
}